// Round 1
// baseline (67.373 us; speedup 1.0000x reference)
//
#include <hip/hip_runtime.h>

// DepthLoss3D: N=4096 (16x16x16), all-pairs masked manhattan -> 3 scalars.
//
// Structure (R4->R5): single fused dispatch, 3 ch x 136 triangular (gi>=gj)
// group-pairs x 256x256 elems, split 4 in x -> 1632 blocks. steps = sc*(gi-gj)
// is block-uniform; gi<gj pairs are exactly zero (skipped); gi==gj scaled 0.5.
//
// Term algebra (R5): for s>=0 the reference per-pair |dm| equals
//     g(d) - 0.2s*[d<0],   g(d) = max3(d-s, 0.2s-d, 0)
// Proof: d>=0 -> matches the old branch; d<0 -> g = 0.2s-d (dominates both
// d-s and 0 when s>=0), minus 0.2s gives -d. s==0 -> g=|d|, count term = 0.
// So per pair: t1=(x-s)-y, t2=(0.2s-x)+y, max3, acc+= -> 4 VALU, plus the
// [d<0] count done ONCE PER WAVE: x is broadcast-uniform (LDS), so
// popcll(ballot(x<y)) is v_cmp + scalar s_bcnt1/s_add (SALU pipe, ~free).
// a[]=x-s, b[]=0.2s-x precomputed per block in LDS. Exact x<y compare keeps
// the d<0 classification bit-identical to the reference.
//
// Reduction: dual accumulators (break the 256-add dep chain) -> wave
// butterfly -> per-wave  acc_w - 0.2s*cnt_w -> block partial, clamped via
// fabsf (the subtraction could round to -0.0; sign bit must stay clear).
// Each block stores its partial as one 32-bit word (relaxed agent atomic)
// into d_ws; 0xAAAAAAAA poison has the SIGN BIT set, so sign-clear == ready.
// Block 0 polls as 8-byte words (4 sequential chains/thread instead of 7),
// reduces per channel, writes d_out (overwrites poison; no extra dispatch).

#define BLOCK 256
#define NTASK_PER_CH 136               // 16*17/2 triangular group pairs
#define SPLIT 4                        // x-split per task
#define NBLK (3 * NTASK_PER_CH * SPLIT)    // 1632
#define PER_CH (NTASK_PER_CH * SPLIT)      // 544 partials per channel
#define NQ (NBLK / 2)                      // 816 qwords polled
#define QPC (PER_CH / 2)                   // 272 qwords per channel

__device__ __forceinline__ int elem_index(int c, int g, int k) {
    // flat (h,w,d) index whose c-th nibble is g, other two nibbles from k
    const int kh = k >> 4, kl = k & 15;
    if (c == 0) return (g << 8) | k;
    if (c == 1) return (kh << 8) | (g << 4) | kl;
    return (kh << 8) | (kl << 4) | g;
}

__global__ __launch_bounds__(BLOCK) void depth_loss_fused(
        const float* __restrict__ pred,
        const float* __restrict__ spac,
        float* __restrict__ partial /* [NBLK] in d_ws */,
        float* __restrict__ out) {
    const int tid  = threadIdx.x;
    const int blk  = blockIdx.x;
    const int task = blk >> 2;          // / SPLIT
    const int part = blk & 3;
    const int c    = (task >= 2 * NTASK_PER_CH) ? 2
                   : (task >= NTASK_PER_CH)     ? 1 : 0;
    int r = task - c * NTASK_PER_CH;

    // triangular decode: row gi has gi+1 entries (gj = 0..gi); uniform loop
    int gi = 0;
    while (r >= gi + 1) { r -= gi + 1; ++gi; }
    const int gj = r;

    const float sc    = spac[c] * 2.0f;                 // spacing * STEP
    const float s     = (float)(gi - gj) * sc;          // block-uniform step
    const float s02   = 0.2f * s;
    const float scale = (gi == gj) ? 0.5f : 1.0f;

    __shared__ float4 xs4[16], as4[16], bs4[16];
    if (tid < 64) {
        const float x = pred[3 * elem_index(c, gi, part * 64 + tid) + c];
        ((float*)xs4)[tid] = x;
        ((float*)as4)[tid] = x - s;     // t1 = a - y  == d - s
        ((float*)bs4)[tid] = s02 - x;   // t2 = b + y  == 0.2s - d
    }
    const float y = pred[3 * elem_index(c, gj, tid) + c];
    __syncthreads();

    float acc0 = 0.0f, acc1 = 0.0f;
    int cnt = 0;                         // wave-uniform: pairs with d<0
#pragma unroll
    for (int i = 0; i < 16; ++i) {
        const float4 x4 = xs4[i];        // same-address broadcast: conflict-free
        const float4 a4 = as4[i];
        const float4 b4 = bs4[i];
        acc0 += fmaxf(fmaxf(a4.x - y, b4.x + y), 0.0f);   // v_max3
        cnt  += (int)__popcll(__ballot(x4.x < y));
        acc1 += fmaxf(fmaxf(a4.y - y, b4.y + y), 0.0f);
        cnt  += (int)__popcll(__ballot(x4.y < y));
        acc0 += fmaxf(fmaxf(a4.z - y, b4.z + y), 0.0f);
        cnt  += (int)__popcll(__ballot(x4.z < y));
        acc1 += fmaxf(fmaxf(a4.w - y, b4.w + y), 0.0f);
        cnt  += (int)__popcll(__ballot(x4.w < y));
    }

    // wave butterfly on acc; cnt already covers the wave's 64x64 pairs
    float acc = acc0 + acc1;
    for (int off = 32; off > 0; off >>= 1) acc += __shfl_down(acc, off, 64);
    __shared__ float wsum[BLOCK / 64];
    const int wave = tid >> 6;
    if ((tid & 63) == 0) wsum[wave] = acc - s02 * (float)cnt;
    __syncthreads();
    if (tid == 0) {
        float t = 0.0f;
#pragma unroll
        for (int w = 0; w < BLOCK / 64; ++w) t += wsum[w];
        t = fabsf(t * scale);            // >= 0; guarantees sign bit clear
        __hip_atomic_store(&partial[blk], t, __ATOMIC_RELAXED,
                           __HIP_MEMORY_SCOPE_AGENT);
    }

    if (blk != 0) return;

    // ---- block 0: poll + final reduce (value doubles as ready-flag) ----
    // 8-byte polls: both halves must have sign bit clear (poison = 0xAA..,
    // sign set). 816 qwords / 256 threads -> <=4 sequential chains.
    float a0 = 0.0f, a1c = 0.0f, a2c = 0.0f;
    const unsigned long long* pq = (const unsigned long long*)partial;
    for (int q = tid; q < NQ; q += BLOCK) {
        unsigned long long v;
        do {
            v = __hip_atomic_load(&pq[q], __ATOMIC_RELAXED,
                                  __HIP_MEMORY_SCOPE_AGENT);
        } while (v & 0x8000000080000000ull);
        const float sv = __uint_as_float((unsigned)v)
                       + __uint_as_float((unsigned)(v >> 32));
        if (q >= 2 * QPC)      a2c += sv;   // qword channel bounds: 272, 544
        else if (q >= QPC)     a1c += sv;
        else                   a0  += sv;
    }
    for (int off = 32; off > 0; off >>= 1) {
        a0  += __shfl_down(a0,  off, 64);
        a1c += __shfl_down(a1c, off, 64);
        a2c += __shfl_down(a2c, off, 64);
    }
    __shared__ float fin[3][BLOCK / 64];
    __syncthreads();                          // LDS reuse barrier
    if ((tid & 63) == 0) { fin[0][wave] = a0; fin[1][wave] = a1c; fin[2][wave] = a2c; }
    __syncthreads();
    if (tid == 0) {
        float t0 = 0.0f, t1 = 0.0f, t2 = 0.0f;
#pragma unroll
        for (int w = 0; w < BLOCK / 64; ++w) {
            t0 += fin[0][w]; t1 += fin[1][w]; t2 += fin[2][w];
        }
        const float inv = 1.0f / (4096.0f * 4096.0f);
        out[0] = t0 * inv;   // overwrites 0xAA poison
        out[1] = t1 * inv;
        out[2] = t2 * inv;
    }
}

extern "C" void kernel_launch(void* const* d_in, const int* in_sizes, int n_in,
                              void* d_out, int out_size, void* d_ws, size_t ws_size,
                              hipStream_t stream) {
    const float* pred = (const float*)d_in[0];   // [4096,3] fp32
    const float* spac = (const float*)d_in[1];   // [3,1]   fp32
    depth_loss_fused<<<NBLK, BLOCK, 0, stream>>>(pred, spac,
                                                 (float*)d_ws, (float*)d_out);
}